// Round 20
// baseline (127.671 us; speedup 1.0000x reference)
//
#include <hip/hip_runtime.h>

#define NBINS    2048          // float bits >> 20 : 8 exp + 3 mantissa bits
#define REPL     2             // 2 replicas; hist padded to 40 KB (codegen lever)
#define HSIZE    (NBINS * REPL + 1024)   // 5120 u64 = 40 KB -> 4 blocks/CU
#define THREADS  256
#define BLOCKS   1024          // 4 blocks/CU x 256 CU; 18 iters/thread
#define CNTSH    44            // count lives in bits [44,64)

// clang native vector type: layout-identical to float4, accepted by
// __builtin_nontemporal_load (HIP_vector_type is not).
typedef float nfloat4 __attribute__((ext_vector_type(4)));

__device__ __forceinline__ void process_elem(
    float g, float p,
    unsigned int& posc, float& ps,
    unsigned long long* hist, unsigned int repl)
{
    // torch-style BCE with log clamp at -100:
    // loss = g*min(-log p,100) + (1-g)*min(-log(1-p),100)
    float nlp = fminf(-__logf(p), 100.0f);
    float nlq = fminf(-__logf(1.0f - p), 100.0f);
    float loss = fmaf(g, nlp - nlq, nlq);     // g*nlp + (1-g)*nlq

    bool isPos = (g >= 0.9f);
    bool isNeg = (g < 0.8f);
    posc += isPos;
    if (isPos) ps += loss;
    if (isNeg) {
        unsigned int b = 0;
        if (loss > 0.0f) {                     // guard -0.0 / nonpositive
            b = __float_as_uint(loss) >> 20;
            if (b > NBINS - 1) b = NBINS - 1;
        }
        // fixed-point quantize (loss <= 100 -> fits u32); pack count|sum
        unsigned long long q =
            (unsigned long long)(unsigned int)(fmaf(loss, 1048576.0f, 0.5f));
        atomicAdd(&hist[(b << 1) | repl], (1ull << CNTSH) | q);
    }
}

__device__ __forceinline__ void process4(
    nfloat4 g, nfloat4 p,
    unsigned int& posc, float& ps,
    unsigned long long* hist, unsigned int repl)
{
    process_elem(g.x, p.x, posc, ps, hist, repl);
    process_elem(g.y, p.y, posc, ps, hist, repl);
    process_elem(g.z, p.z, posc, ps, hist, repl);
    process_elem(g.w, p.w, posc, ps, hist, repl);
}

__global__ __launch_bounds__(THREADS) void pass1(
    const float* __restrict__ gt, const float* __restrict__ pred,
    unsigned int* __restrict__ counts, unsigned long long* __restrict__ sums,
    unsigned int* __restrict__ posCnt, double* __restrict__ psum,
    int n4, int nTail, long long tailBase)
{
    // 40 KB LDS: 32 KB live histogram + 8 KB pad. Sets the scheduler's
    // occupancy target to 4 blocks/CU (16 waves) with a 128-VGPR budget --
    // the only point that doubles waves vs the 64KB regime while keeping
    // the proven fat codegen in budget.
    __shared__ unsigned long long hist[HSIZE];
    for (int i = threadIdx.x; i < NBINS * REPL; i += THREADS) hist[i] = 0ull;
    __syncthreads();

    unsigned int posc = 0;
    float ps = 0.0f;
    const unsigned int repl = threadIdx.x & (REPL - 1);

    const nfloat4* g4p = (const nfloat4*)gt;
    const nfloat4* p4p = (const nfloat4*)pred;
    const int stride = gridDim.x * blockDim.x;
    int i = blockIdx.x * blockDim.x + threadIdx.x;

    // batches of 4 grid-stride iterations; NON-TEMPORAL loads bypass the
    // L2/L3 hit path (R19: +20% on profiled dispatches).
    for (; i + 3 * stride < n4; i += 4 * stride) {
        nfloat4 g0 = __builtin_nontemporal_load(g4p + i);
        nfloat4 p0 = __builtin_nontemporal_load(p4p + i);
        nfloat4 g1 = __builtin_nontemporal_load(g4p + i + stride);
        nfloat4 p1 = __builtin_nontemporal_load(p4p + i + stride);
        nfloat4 g2 = __builtin_nontemporal_load(g4p + i + 2 * stride);
        nfloat4 p2 = __builtin_nontemporal_load(p4p + i + 2 * stride);
        nfloat4 g3 = __builtin_nontemporal_load(g4p + i + 3 * stride);
        nfloat4 p3 = __builtin_nontemporal_load(p4p + i + 3 * stride);

        process4(g0, p0, posc, ps, hist, repl);
        process4(g1, p1, posc, ps, hist, repl);
        process4(g2, p2, posc, ps, hist, repl);
        process4(g3, p3, posc, ps, hist, repl);
    }
    for (; i < n4; i += stride) {
        nfloat4 g4 = __builtin_nontemporal_load(g4p + i);
        nfloat4 p4 = __builtin_nontemporal_load(p4p + i);
        process4(g4, p4, posc, ps, hist, repl);
    }
    if (blockIdx.x == 0 && threadIdx.x < nTail) {
        long long e = tailBase + threadIdx.x;
        process_elem(gt[e], pred[e], posc, ps, hist, repl);
    }

    __syncthreads();
    // flush: fold 2 replicas (packed fields add safely: per-block count
    // <= 18432 < 2^20, sum < 2^44), then 1 u32 + 1 u64 atomic per hot bin
    for (int b = threadIdx.x; b < NBINS; b += THREADS) {
        unsigned long long v = hist[(b << 1) | 0] + hist[(b << 1) | 1];
        if (v) {
            atomicAdd(&counts[b], (unsigned int)(v >> CNTSH));
            atomicAdd(&sums[b],   v & ((1ull << CNTSH) - 1));
        }
    }

    // wave-64 reduce scalars, one atomic per wave
    double pd = (double)ps;
    for (int off = 32; off > 0; off >>= 1) {
        posc += __shfl_down(posc, off);
        pd   += __shfl_down(pd, off);
    }
    if ((threadIdx.x & 63) == 0) {
        if (posc) atomicAdd(posCnt, posc);
        atomicAdd(psum, pd);
    }
}

__global__ __launch_bounds__(256) void finalize(
    const unsigned int* __restrict__ counts,
    const unsigned long long* __restrict__ sums,
    const unsigned int* __restrict__ posCnt, const double* __restrict__ psum,
    float* __restrict__ out)
{
    __shared__ unsigned long long scnt[256];
    __shared__ double             ssum[256];
    __shared__ int                s_chunk;
    __shared__ double             s_topk;

    const int t = threadIdx.x;
    const int BPT = NBINS / 256;          // 8 bins per thread
    const int base = t * BPT;
    const double INVFIX = 1.0 / 1048576.0;

    unsigned long long c = 0; double s = 0.0;
    #pragma unroll
    for (int i = 0; i < BPT; ++i) {
        c += counts[base + i];
        s += (double)sums[base + i] * INVFIX;
    }
    scnt[t] = c; ssum[t] = s;
    if (t == 0) { s_chunk = -1; s_topk = 0.0; }
    __syncthreads();

    // inclusive suffix scan over 256 chunks
    for (int off = 1; off < 256; off <<= 1) {
        unsigned long long cv = (t + off < 256) ? scnt[t + off] : 0ull;
        double             sv = (t + off < 256) ? ssum[t + off] : 0.0;
        __syncthreads();
        scnt[t] += cv; ssum[t] += sv;
        __syncthreads();
    }

    const unsigned int pos = posCnt[0];
    const unsigned long long total = scnt[0];   // exact negative count

    // k = floor(min(max(pos,1)*3.0, neg)) in f32, mirroring reference
    float kf = fminf(fmaxf((float)pos, 1.0f) * 3.0f, (float)total);
    long long k = (long long)floorf(kf);

    unsigned long long Sincl = scnt[t];
    unsigned long long Sexcl = (t < 255) ? scnt[t + 1] : 0ull;
    double SexclSum          = (t < 255) ? ssum[t + 1] : 0.0;

    if (k > 0 && Sexcl < (unsigned long long)k && Sincl >= (unsigned long long)k) {
        double topk = SexclSum;
        unsigned long long need = (unsigned long long)k - Sexcl;
        for (int i = BPT - 1; i >= 0 && need > 0; --i) {
            int b = base + i;
            unsigned long long cb = counts[b];
            if (!cb) continue;
            double sb = (double)sums[b] * INVFIX;
            if (cb <= need) {
                topk += sb;
                need -= cb;
            } else {
                // partial bin: uniform-within-bin model anchored at bin mean
                float lo = __uint_as_float((unsigned)b << 20);
                float hi = (b + 1 < NBINS) ? __uint_as_float((unsigned)(b + 1) << 20) : lo;
                double w = (double)hi - (double)lo;
                double n = (double)cb;
                double r = (double)need;
                double mean = sb / n;
                topk += r * (mean + 0.5 * w * (1.0 - r / n));
                need = 0;
            }
        }
        s_topk = topk;
        s_chunk = t;
    }
    __syncthreads();

    if (t == 0) {
        double topk = (s_chunk >= 0) ? s_topk : 0.0;
        float denf = (float)pos + (float)k;
        denf += 1e-4f;
        double res = (3.0 * (*psum) + topk) / (double)denf;
        out[0] = (float)res;
    }
}

extern "C" void kernel_launch(void* const* d_in, const int* in_sizes, int n_in,
                              void* d_out, int out_size, void* d_ws, size_t ws_size,
                              hipStream_t stream) {
    const float* gt   = (const float*)d_in[0];
    const float* pred = (const float*)d_in[1];
    float* out = (float*)d_out;

    // ws: [0,8) double psum | [8,12) u32 pos | pad | [16,16+8K) u32 counts
    //     | [16+8K, 16+8K+16K) u64 sums
    double*             psum   = (double*)d_ws;
    unsigned int*       posCnt = (unsigned int*)((char*)d_ws + 8);
    unsigned int*       counts = (unsigned int*)((char*)d_ws + 16);
    unsigned long long* sums   = (unsigned long long*)((char*)d_ws + 16 + NBINS * sizeof(unsigned int));

    size_t zbytes = 16 + (size_t)NBINS * (sizeof(unsigned int) + sizeof(unsigned long long));
    hipMemsetAsync(d_ws, 0, zbytes, stream);

    long long n = (long long)in_sizes[0];
    int n4 = (int)(n >> 2);
    int nTail = (int)(n & 3);
    long long tailBase = (long long)n4 * 4;

    pass1<<<dim3(BLOCKS), dim3(THREADS), 0, stream>>>(
        gt, pred, counts, sums, posCnt, psum, n4, nTail, tailBase);
    finalize<<<dim3(1), dim3(256), 0, stream>>>(counts, sums, posCnt, psum, out);
}

// Round 21
// 88.298 us; speedup vs baseline: 1.4459x; 1.4459x over previous
//
#include <hip/hip_runtime.h>

#define NBINS    2048          // float bits >> 20 : 8 exp + 3 mantissa bits
#define REPL     4             // per-lane-group replicas (R2-proven codegen shape)
#define THREADS  256
#define BLOCKS   512           // 2 blocks/CU, 64 KB LDS -> fat-codegen regime
#define CNTSH    44            // count lives in bits [44,64)

// clang native vector type: layout-identical to float4, accepted by
// __builtin_nontemporal_load (HIP_vector_type is not).
typedef float nfloat4 __attribute__((ext_vector_type(4)));

__device__ __forceinline__ void process_elem(
    float g, float p,
    unsigned int& posc, float& ps,
    unsigned long long* hist, unsigned int repl)
{
    // torch-style BCE with log clamp at -100:
    // loss = g*min(-log p,100) + (1-g)*min(-log(1-p),100)
    float nlp = fminf(-__logf(p), 100.0f);
    float nlq = fminf(-__logf(1.0f - p), 100.0f);
    float loss = fmaf(g, nlp - nlq, nlq);     // g*nlp + (1-g)*nlq

    bool isPos = (g >= 0.9f);
    bool isNeg = (g < 0.8f);
    posc += isPos;
    if (isPos) ps += loss;
    if (isNeg) {
        unsigned int b = 0;
        if (loss > 0.0f) {                     // guard -0.0 / nonpositive
            b = __float_as_uint(loss) >> 20;
            if (b > NBINS - 1) b = NBINS - 1;
        }
        // fixed-point quantize (loss <= 100 -> fits u32); pack count|sum
        unsigned long long q =
            (unsigned long long)(unsigned int)(fmaf(loss, 1048576.0f, 0.5f));
        atomicAdd(&hist[(b << 2) | repl], (1ull << CNTSH) | q);
    }
}

__device__ __forceinline__ void process4(
    nfloat4 g, nfloat4 p,
    unsigned int& posc, float& ps,
    unsigned long long* hist, unsigned int repl)
{
    process_elem(g.x, p.x, posc, ps, hist, repl);
    process_elem(g.y, p.y, posc, ps, hist, repl);
    process_elem(g.z, p.z, posc, ps, hist, repl);
    process_elem(g.w, p.w, posc, ps, hist, repl);
}

__global__ __launch_bounds__(THREADS) void pass1(
    const float* __restrict__ gt, const float* __restrict__ pred,
    unsigned int* __restrict__ counts, unsigned long long* __restrict__ sums,
    unsigned int* __restrict__ posCnt, double* __restrict__ psum,
    int n4, int nTail, long long tailBase)
{
    __shared__ unsigned long long hist[NBINS * REPL];
    for (int i = threadIdx.x; i < NBINS * REPL; i += THREADS) hist[i] = 0ull;
    __syncthreads();

    unsigned int posc = 0;
    float ps = 0.0f;
    const unsigned int repl = threadIdx.x & (REPL - 1);

    const nfloat4* g4p = (const nfloat4*)gt;
    const nfloat4* p4p = (const nfloat4*)pred;
    const int stride = gridDim.x * blockDim.x;
    int i = blockIdx.x * blockDim.x + threadIdx.x;

    // batches of 4 grid-stride iterations; loads are NON-TEMPORAL to bypass
    // the L2/L3 hit path (R19: +20% on profiled dispatches vs temporal).
    // 64 KB LDS keeps the compiler in the fat-codegen regime (88 VGPR, no
    // spill) -- the only point on the {16,32,40,64} KB ladder that does.
    for (; i + 3 * stride < n4; i += 4 * stride) {
        nfloat4 g0 = __builtin_nontemporal_load(g4p + i);
        nfloat4 p0 = __builtin_nontemporal_load(p4p + i);
        nfloat4 g1 = __builtin_nontemporal_load(g4p + i + stride);
        nfloat4 p1 = __builtin_nontemporal_load(p4p + i + stride);
        nfloat4 g2 = __builtin_nontemporal_load(g4p + i + 2 * stride);
        nfloat4 p2 = __builtin_nontemporal_load(p4p + i + 2 * stride);
        nfloat4 g3 = __builtin_nontemporal_load(g4p + i + 3 * stride);
        nfloat4 p3 = __builtin_nontemporal_load(p4p + i + 3 * stride);

        process4(g0, p0, posc, ps, hist, repl);
        process4(g1, p1, posc, ps, hist, repl);
        process4(g2, p2, posc, ps, hist, repl);
        process4(g3, p3, posc, ps, hist, repl);
    }
    for (; i < n4; i += stride) {
        nfloat4 g4 = __builtin_nontemporal_load(g4p + i);
        nfloat4 p4 = __builtin_nontemporal_load(p4p + i);
        process4(g4, p4, posc, ps, hist, repl);
    }
    if (blockIdx.x == 0 && threadIdx.x < nTail) {
        long long e = tailBase + threadIdx.x;
        process_elem(gt[e], pred[e], posc, ps, hist, repl);
    }

    __syncthreads();
    // flush: fold 4 replicas (packed fields add safely: per-block sum < 2^44,
    // count < 2^20), then one u32 + one u64 global atomic per active bin
    for (int b = threadIdx.x; b < NBINS; b += THREADS) {
        unsigned long long v = hist[(b << 2) | 0] + hist[(b << 2) | 1]
                             + hist[(b << 2) | 2] + hist[(b << 2) | 3];
        if (v) {
            atomicAdd(&counts[b], (unsigned int)(v >> CNTSH));
            atomicAdd(&sums[b],   v & ((1ull << CNTSH) - 1));
        }
    }

    // wave-64 reduce scalars, one atomic per wave
    double pd = (double)ps;
    for (int off = 32; off > 0; off >>= 1) {
        posc += __shfl_down(posc, off);
        pd   += __shfl_down(pd, off);
    }
    if ((threadIdx.x & 63) == 0) {
        if (posc) atomicAdd(posCnt, posc);
        atomicAdd(psum, pd);
    }
}

__global__ __launch_bounds__(256) void finalize(
    const unsigned int* __restrict__ counts,
    const unsigned long long* __restrict__ sums,
    const unsigned int* __restrict__ posCnt, const double* __restrict__ psum,
    float* __restrict__ out)
{
    __shared__ unsigned long long scnt[256];
    __shared__ double             ssum[256];
    __shared__ int                s_chunk;
    __shared__ double             s_topk;

    const int t = threadIdx.x;
    const int BPT = NBINS / 256;          // 8 bins per thread
    const int base = t * BPT;
    const double INVFIX = 1.0 / 1048576.0;

    unsigned long long c = 0; double s = 0.0;
    #pragma unroll
    for (int i = 0; i < BPT; ++i) {
        c += counts[base + i];
        s += (double)sums[base + i] * INVFIX;
    }
    scnt[t] = c; ssum[t] = s;
    if (t == 0) { s_chunk = -1; s_topk = 0.0; }
    __syncthreads();

    // inclusive suffix scan over 256 chunks
    for (int off = 1; off < 256; off <<= 1) {
        unsigned long long cv = (t + off < 256) ? scnt[t + off] : 0ull;
        double             sv = (t + off < 256) ? ssum[t + off] : 0.0;
        __syncthreads();
        scnt[t] += cv; ssum[t] += sv;
        __syncthreads();
    }

    const unsigned int pos = posCnt[0];
    const unsigned long long total = scnt[0];   // exact negative count

    // k = floor(min(max(pos,1)*3.0, neg)) in f32, mirroring reference
    float kf = fminf(fmaxf((float)pos, 1.0f) * 3.0f, (float)total);
    long long k = (long long)floorf(kf);

    unsigned long long Sincl = scnt[t];
    unsigned long long Sexcl = (t < 255) ? scnt[t + 1] : 0ull;
    double SexclSum          = (t < 255) ? ssum[t + 1] : 0.0;

    if (k > 0 && Sexcl < (unsigned long long)k && Sincl >= (unsigned long long)k) {
        double topk = SexclSum;
        unsigned long long need = (unsigned long long)k - Sexcl;
        for (int i = BPT - 1; i >= 0 && need > 0; --i) {
            int b = base + i;
            unsigned long long cb = counts[b];
            if (!cb) continue;
            double sb = (double)sums[b] * INVFIX;
            if (cb <= need) {
                topk += sb;
                need -= cb;
            } else {
                // partial bin: uniform-within-bin model anchored at bin mean
                float lo = __uint_as_float((unsigned)b << 20);
                float hi = (b + 1 < NBINS) ? __uint_as_float((unsigned)(b + 1) << 20) : lo;
                double w = (double)hi - (double)lo;
                double n = (double)cb;
                double r = (double)need;
                double mean = sb / n;
                topk += r * (mean + 0.5 * w * (1.0 - r / n));
                need = 0;
            }
        }
        s_topk = topk;
        s_chunk = t;
    }
    __syncthreads();

    if (t == 0) {
        double topk = (s_chunk >= 0) ? s_topk : 0.0;
        float denf = (float)pos + (float)k;
        denf += 1e-4f;
        double res = (3.0 * (*psum) + topk) / (double)denf;
        out[0] = (float)res;
    }
}

extern "C" void kernel_launch(void* const* d_in, const int* in_sizes, int n_in,
                              void* d_out, int out_size, void* d_ws, size_t ws_size,
                              hipStream_t stream) {
    const float* gt   = (const float*)d_in[0];
    const float* pred = (const float*)d_in[1];
    float* out = (float*)d_out;

    // ws: [0,8) double psum | [8,12) u32 pos | pad | [16,16+8K) u32 counts
    //     | [16+8K, 16+8K+16K) u64 sums
    double*             psum   = (double*)d_ws;
    unsigned int*       posCnt = (unsigned int*)((char*)d_ws + 8);
    unsigned int*       counts = (unsigned int*)((char*)d_ws + 16);
    unsigned long long* sums   = (unsigned long long*)((char*)d_ws + 16 + NBINS * sizeof(unsigned int));

    size_t zbytes = 16 + (size_t)NBINS * (sizeof(unsigned int) + sizeof(unsigned long long));
    hipMemsetAsync(d_ws, 0, zbytes, stream);

    long long n = (long long)in_sizes[0];
    int n4 = (int)(n >> 2);
    int nTail = (int)(n & 3);
    long long tailBase = (long long)n4 * 4;

    pass1<<<dim3(BLOCKS), dim3(THREADS), 0, stream>>>(
        gt, pred, counts, sums, posCnt, psum, n4, nTail, tailBase);
    finalize<<<dim3(1), dim3(256), 0, stream>>>(counts, sums, posCnt, psum, out);
}